// Round 1
// baseline (226.925 us; speedup 1.0000x reference)
//
#include <hip/hip_runtime.h>
#include <hip/hip_bf16.h>

#define C_DIM 100000
#define N_ROW 512
#define K_DIM 512
#define OUT_HALF 51200000  // N_ROW * C_DIM

#define SCALE_F 64.0f
#define ALPHA_F 0.1f
#define COS_M_F 0.87758256189037276f
#define SIN_M_F 0.47942553860420301f
#define THRESH_F (-0.87758256189037276f)
#define MM_F 0.23971276930210151f

typedef __attribute__((ext_vector_type(8))) short short8;
typedef __attribute__((ext_vector_type(4))) short short4v;
typedef __attribute__((ext_vector_type(4))) float f32x4;
typedef __attribute__((ext_vector_type(2))) int i32x2;

static __device__ __forceinline__ unsigned short f2bf(float f) {
  union { float f; unsigned u; } x; x.f = f;
  unsigned r = x.u + 0x7fffu + ((x.u >> 16) & 1u);
  return (unsigned short)(r >> 16);
}

// ---------------------------------------------------------------------------
// N1: normalize embedding rows, write bf16 A in MFMA-fragment-ready layout:
// Asw[kstep s][msub][lane][j] = emb_n[16*msub + (lane&15)]
//                                    [32*s + 4*(lane>>4) + (j&3) + 16*(j>>2)]
// ---------------------------------------------------------------------------
__global__ __launch_bounds__(64) void prep_emb(const float* __restrict__ emb,
                                               unsigned short* __restrict__ Asw) {
  const int m = blockIdx.x;
  const int t = threadIdx.x;
  const float* row = emb + (size_t)m * K_DIM;
  float ss = 0.f;
#pragma unroll
  for (int d = 0; d < 8; ++d) { float v = row[t + 64 * d]; ss += v * v; }
#pragma unroll
  for (int off = 32; off > 0; off >>= 1) ss += __shfl_xor(ss, off, 64);
  const float inv = rsqrtf(ss);
  const int s = t >> 2, g = t & 3;
  short8 pack;
#pragma unroll
  for (int j = 0; j < 8; ++j) {
    int k = 32 * s + 4 * g + (j & 3) + 16 * (j >> 2);
    pack[j] = (short)f2bf(row[k] * inv);
  }
  size_t idx = ((size_t)(s * 32 + (m >> 4)) * 64 + (m & 15) + 16 * g) * 8;
  *(short8*)(Asw + idx) = pack;
}

// ---------------------------------------------------------------------------
// N3: per-row target logit in f32: target[i] = clip(<emb_i, K[:,lab]> /
//                                  (||emb_i|| * ||K[:,lab]||), -1, 1)
// ---------------------------------------------------------------------------
__global__ __launch_bounds__(64) void target_k(const float* __restrict__ emb,
                                               const float* __restrict__ Kmat,
                                               const int* __restrict__ labels,
                                               float* __restrict__ target) {
  const int i = blockIdx.x;
  const int t = threadIdx.x;
  const int lab = labels[i];
  const float* row = emb + (size_t)i * K_DIM;
  float dot = 0.f, ess = 0.f, kss = 0.f;
#pragma unroll
  for (int d0 = 0; d0 < 8; ++d0) {
    int d = t + 64 * d0;
    float e = row[d];
    float k = Kmat[(size_t)d * C_DIM + lab];
    dot += e * k; ess += e * e; kss += k * k;
  }
#pragma unroll
  for (int off = 32; off > 0; off >>= 1) {
    dot += __shfl_xor(dot, off, 64);
    ess += __shfl_xor(ess, off, 64);
    kss += __shfl_xor(kss, off, 64);
  }
  if (t == 0) {
    float tg = dot * rsqrtf(ess) * rsqrtf(kss);
    tg = fminf(1.f, fmaxf(-1.f, tg));
    target[i] = tg;
  }
}

// ---------------------------------------------------------------------------
// N4: t_new = mean(target)*ALPHA + (1-ALPHA)*t; per-row cos_theta_m and
// final_target_logit
// ---------------------------------------------------------------------------
__global__ __launch_bounds__(512) void rowdata_k(const float* __restrict__ target,
                                                 const float* __restrict__ t_in,
                                                 float* __restrict__ ctm,
                                                 float* __restrict__ ftl,
                                                 float* __restrict__ tnew) {
  __shared__ float red[512];
  const int i = threadIdx.x;
  const float tg = target[i];
  red[i] = tg;
  __syncthreads();
  for (int s = 256; s > 0; s >>= 1) {
    if (i < s) red[i] += red[i + s];
    __syncthreads();
  }
  const float t_new = red[0] * (1.0f / 512.0f) * ALPHA_F + (1.f - ALPHA_F) * t_in[0];
  const float st = sqrtf(fmaxf(0.f, 1.f - tg * tg));
  const float cm = tg * COS_M_F - st * SIN_M_F;
  ctm[i] = cm;
  ftl[i] = (tg > THRESH_F) ? cm : (tg - MM_F);
  if (i == 0) tnew[0] = t_new;
}

// ---------------------------------------------------------------------------
// G: fused GEMM + epilogue. BM=512 (full M), BN=64, BK=32, 8 waves.
// Swapped operands: mfma(X=K-tile fragment, Y=emb fragment) -> D[c][m].
// Kernel matrix read once; per-column sumsq accumulated during staging.
// ---------------------------------------------------------------------------
__global__ __launch_bounds__(512, 2) void gemm_ep(
    const float* __restrict__ Kmat,
    const unsigned short* __restrict__ Asw,
    const float* __restrict__ ctm_a,
    const float* __restrict__ ftl_a,
    const float* __restrict__ tnew_p,
    const int* __restrict__ labels,
    float* __restrict__ out) {
  // B tile double buffer: [buf][n-subtile 0..3][32k x 16n] bf16 (tr-read layout)
  __shared__ unsigned short Bl[2][4][512];
  __shared__ float ssq_sh[32][64];
  __shared__ float invn[64];

  const int tid = threadIdx.x;
  const int wv = tid >> 6;
  const int lane = tid & 63;
  const int c0 = blockIdx.x * 64;
  const int ks = tid >> 4;  // 0..31: k row in tile
  const int q = tid & 15;   // quad of 4 columns
  const int cg = c0 + q * 4;
  const bool cok = (cg < C_DIM);  // full float4 in-bounds (C%4==0)

  f32x4 acc[4][4];
#pragma unroll
  for (int i = 0; i < 4; ++i)
#pragma unroll
    for (int j = 0; j < 4; ++j) acc[i][j] = (f32x4){0.f, 0.f, 0.f, 0.f};

  f32x4 ssq = (f32x4){0.f, 0.f, 0.f, 0.f};

  // prologue: stage tile 0 into buf 0
  {
    f32x4 bv = (f32x4){0.f, 0.f, 0.f, 0.f};
    if (cok) bv = *(const f32x4*)(Kmat + (size_t)ks * C_DIM + cg);
    ssq += bv * bv;
    unsigned pk0 = (unsigned)f2bf(bv[0]) | ((unsigned)f2bf(bv[1]) << 16);
    unsigned pk1 = (unsigned)f2bf(bv[2]) | ((unsigned)f2bf(bv[3]) << 16);
    i32x2 wr; wr[0] = (int)pk0; wr[1] = (int)pk1;
    *(i32x2*)&Bl[0][q >> 2][ks * 16 + (q & 3) * 4] = wr;
  }
  __syncthreads();

  const unsigned ldsbase = (unsigned)(uintptr_t)&Bl[0][0][0];

  for (int s = 0; s < 16; ++s) {
    // issue next tile's global loads early (latency hides under MFMA)
    f32x4 nv = (f32x4){0.f, 0.f, 0.f, 0.f};
    if (s < 15 && cok)
      nv = *(const f32x4*)(Kmat + (size_t)((s + 1) * 32 + ks) * C_DIM + cg);

    // Y fragments (emb side) straight from global (L2-resident, pre-swizzled)
    short8 Y[4];
#pragma unroll
    for (int j = 0; j < 4; ++j)
      Y[j] = *(const short8*)(Asw + (size_t)((s * 32 + wv * 4 + j) * 64 + lane) * 8);

    // X fragments (K side) via hardware transpose reads from LDS
    short8 X[4];
    const unsigned base = ldsbase + (unsigned)((s & 1) * 4096) + (unsigned)lane * 8;
#pragma unroll
    for (int cs = 0; cs < 4; ++cs) {
      i32x2 t0, t1;
      unsigned a = base + (unsigned)cs * 1024;
      asm volatile("ds_read_b64_tr_b16 %0, %2\n\t"
                   "ds_read_b64_tr_b16 %1, %2 offset:512"
                   : "=&v"(t0), "=&v"(t1)
                   : "v"(a));
      short4v lo = __builtin_bit_cast(short4v, t0);
      short4v hi = __builtin_bit_cast(short4v, t1);
      X[cs] = __builtin_shufflevector(lo, hi, 0, 1, 2, 3, 4, 5, 6, 7);
    }
    asm volatile("s_waitcnt lgkmcnt(0)" ::: "memory");
    __builtin_amdgcn_sched_barrier(0);

#pragma unroll
    for (int cs = 0; cs < 4; ++cs)
#pragma unroll
      for (int ms = 0; ms < 4; ++ms)
        acc[cs][ms] =
            __builtin_amdgcn_mfma_f32_16x16x32_bf16(X[cs], Y[ms], acc[cs][ms], 0, 0, 0);

    if (s < 15) {
      ssq += nv * nv;
      unsigned pk0 = (unsigned)f2bf(nv[0]) | ((unsigned)f2bf(nv[1]) << 16);
      unsigned pk1 = (unsigned)f2bf(nv[2]) | ((unsigned)f2bf(nv[3]) << 16);
      i32x2 wr; wr[0] = (int)pk0; wr[1] = (int)pk1;
      *(i32x2*)((char*)&Bl[0][0][0] + (size_t)(((s + 1) & 1) * 4096) +
                (size_t)(q >> 2) * 1024 + (size_t)(ks * 16 + (q & 3) * 4) * 2) = wr;
    }
    __syncthreads();
  }

  // reduce per-column sum of squares -> inverse norms
  *(f32x4*)&ssq_sh[ks][q * 4] = ssq;
  __syncthreads();
  if (tid < 64) {
    float ssum = 0.f;
#pragma unroll
    for (int k = 0; k < 32; ++k) ssum += ssq_sh[k][tid];
    invn[tid] = rsqrtf(fmaxf(ssum, 1e-30f));
  }
  __syncthreads();

  // fused epilogue
  const float t_new = tnew_p[0];
  const int mb = (wv << 6) + (lane & 15);
  float ctm_r[4], ftl_r[4];
  int lab_r[4];
#pragma unroll
  for (int j = 0; j < 4; ++j) {
    int m = mb + 16 * j;
    ctm_r[j] = ctm_a[m];
    ftl_r[j] = ftl_a[m];
    lab_r[j] = labels[m];
  }
  const int cq = (lane >> 4) * 4;

#pragma unroll
  for (int cs = 0; cs < 4; ++cs) {
    const int cl = cs * 16 + cq;
    const int c = c0 + cl;
    if (c >= C_DIM) continue;  // float4 fully out of range (c%4==0, C%4==0)
    const f32x4 inv4 = *(const f32x4*)&invn[cl];
#pragma unroll
    for (int ms = 0; ms < 4; ++ms) {
      const int m = mb + 16 * ms;
      f32x4 a = acc[cs][ms];
      f32x4 og, ct;
#pragma unroll
      for (int r = 0; r < 4; ++r) {
        float cosv = a[r] * inv4[r];
        cosv = fminf(1.f, fmaxf(-1.f, cosv));
        og[r] = cosv * SCALE_F;
        float hard = cosv * (t_new + cosv);
        float v = (cosv > ctm_r[ms]) ? hard : cosv;
        if (c + r == lab_r[ms]) v = ftl_r[ms];
        ct[r] = v * SCALE_F;
      }
      const size_t o = (size_t)m * C_DIM + c;
      *(f32x4*)(out + o) = ct;
      *(f32x4*)(out + OUT_HALF + o) = og;
    }
  }
}

extern "C" void kernel_launch(void* const* d_in, const int* in_sizes, int n_in,
                              void* d_out, int out_size, void* d_ws, size_t ws_size,
                              hipStream_t stream) {
  const float* emb = (const float*)d_in[0];
  const float* Kmat = (const float*)d_in[1];
  const float* t_in = (const float*)d_in[2];
  const int* labels = (const int*)d_in[3];
  float* out = (float*)d_out;

  unsigned short* Asw = (unsigned short*)d_ws;                  // 512 KiB
  float* target = (float*)((char*)d_ws + 524288);               // 512 f32
  float* ctm = target + 512;
  float* ftl = ctm + 512;
  float* tnew = ftl + 512;

  prep_emb<<<512, 64, 0, stream>>>(emb, Asw);
  target_k<<<512, 64, 0, stream>>>(emb, Kmat, labels, target);
  rowdata_k<<<1, 512, 0, stream>>>(target, t_in, ctm, ftl, tnew);

  const int grid = (C_DIM + 63) / 64;  // 1563
  gemm_ep<<<grid, 512, 0, stream>>>(Kmat, Asw, ctm, ftl, tnew, labels, out);
}